// Round 4
// baseline (1326.882 us; speedup 1.0000x reference)
//
#include <hip/hip_runtime.h>
#include <hip/hip_bf16.h>

// ---------------------------------------------------------------------------
// SeqAttnMatch, fp32 in/out, B=64, L=1024, H=128.
// Precision plan: proj & QK^T in split-bf16 (hi+lo, 3-MFMA products -> ~fp32
// scores, since softmax amplifies score noise ~8x); softmax fp32; PV in f16
// (P rounding cancels between numerator and l). Mask encoding auto-detected.
// Two groups of 32 batches keep workspace at the proven 32MB+64KB footprint.
// ---------------------------------------------------------------------------

typedef __attribute__((ext_vector_type(8))) short    s8v;  // 8 bf16 = 16B
typedef __attribute__((ext_vector_type(4))) short    s4v;  // 4 bf16 = 8B
typedef __attribute__((ext_vector_type(8))) _Float16 h8v;  // 8 f16 = 16B
typedef __attribute__((ext_vector_type(4))) _Float16 h4v;  // 4 f16 = 8B
typedef __attribute__((ext_vector_type(4))) float    f4v;

#define BDIM 256
#define GROUP_ROWS 32768          // 32 batches x 1024
#define PLANE ((size_t)GROUP_ROWS * 128)

__device__ __forceinline__ f4v mfma_bf16(s8v a, s8v b, f4v c) {
    return __builtin_amdgcn_mfma_f32_16x16x32_bf16(a, b, c, 0, 0, 0);
}
__device__ __forceinline__ f4v mfma_f16(h8v a, h8v b, f4v c) {
    return __builtin_amdgcn_mfma_f32_16x16x32_f16(a, b, c, 0, 0, 0);
}
__device__ __forceinline__ short f2bf(float x) {
    return __builtin_bit_cast(short, __float2bfloat16(x));
}
__device__ __forceinline__ float bf2f(short x) {
    return __builtin_bit_cast(float, (unsigned)((unsigned short)x) << 16);
}
__device__ __forceinline__ void split2(float v, short& h, short& l) {
    h = f2bf(v);
    l = f2bf(v - bf2f(h));
}

// ---------------------------------------------------------------------------
// Mask normalization -> uint8 0/1 (detector proven working in round 3).
// ---------------------------------------------------------------------------
__global__ __launch_bounds__(1024) void mask_prep(
    const unsigned int* __restrict__ raw, unsigned char* __restrict__ nm)
{
    __shared__ unsigned int sOrAll, sOrOdd;
    if (threadIdx.x == 0) { sOrAll = 0u; sOrOdd = 0u; }
    __syncthreads();
    unsigned int oa = 0u, oo = 0u;
    for (int i = threadIdx.x; i < 16384; i += 1024) {
        unsigned int v = raw[i];
        oa |= v;
        if (i & 1) oo |= v;
    }
    atomicOr(&sOrAll, oa);
    atomicOr(&sOrOdd, oo);
    __syncthreads();
    const unsigned int orv = sOrAll, oro = sOrOdd;
    int mode;  // 0 = 4B stride, 1 = uint8, 2 = 2B stride, 3 = int64
    if (orv <= 1u)                       mode = (orv == 1u && oro == 0u) ? 3 : 0;
    else if ((orv & 0xFEFEFEFEu) == 0u)  mode = 1;
    else if ((orv & 0x0000FFFFu) == 0u)  mode = 0;
    else                                 mode = 2;
    const unsigned char*  b8  = (const unsigned char*)raw;
    const unsigned short* b16 = (const unsigned short*)raw;
    for (int j = threadIdx.x; j < 65536; j += 1024) {
        unsigned int v;
        if (mode == 0)      v = raw[j];
        else if (mode == 1) v = b8[j];
        else if (mode == 2) v = b16[j];
        else                v = raw[2 * j] | raw[2 * j + 1];
        nm[j] = v ? 1 : 0;
    }
}

// swizzled column index for pad-free W tiles (breaks power-of-2 conflicts)
__device__ __forceinline__ int wsw(int r, int kofs) {
    return (((kofs >> 3) ^ (r & 15)) << 3) | (kofs & 7);
}

// ---------------------------------------------------------------------------
// Projection (split-bf16): P = relu(In @ W^T + b), out as hi/lo bf16 planes.
// 1024 blocks/group: 0..511 -> x rows, 512..1023 -> y rows; 64 rows/block.
// ---------------------------------------------------------------------------
__global__ __launch_bounds__(BDIM) void proj_kernel(
    const float* __restrict__ X, const float* __restrict__ Y,
    const float* __restrict__ W, const float* __restrict__ bias,
    short* __restrict__ XPh, short* __restrict__ XPl,
    short* __restrict__ YPh, short* __restrict__ YPl)
{
    __shared__ short sWh[128][128];   // xor-swizzled, 64KB total with sWl
    __shared__ short sWl[128][128];

    const int t = threadIdx.x, blk = blockIdx.x;
    const float* src; short *dsth, *dstl; int row0;
    if (blk < 512) { src = X; dsth = XPh; dstl = XPl; row0 = blk * 64; }
    else           { src = Y; dsth = YPh; dstl = YPl; row0 = (blk - 512) * 64; }

    for (int it = 0; it < 16; ++it) {
        int idx = t + it * BDIM;               // 0..4095
        int r = idx >> 5, c4 = (idx & 31) * 4;
        f4v v = *(const f4v*)&W[r * 128 + c4];
        s4v h, l;
        for (int k = 0; k < 4; ++k) { short hh, ll; split2(v[k], hh, ll); h[k] = hh; l[k] = ll; }
        int cs = wsw(r, c4);
        *(s4v*)&sWh[r][cs] = h;
        *(s4v*)&sWl[r][cs] = l;
    }

    // A fragments straight from global fp32 (quads cover full 128B lines)
    const int wave = t >> 6, lane = t & 63, c = lane & 15, q = lane >> 4;
    s8v ah[4], al[4];
    {
        const float* xr = src + (size_t)(row0 + wave * 16 + c) * 128;
        for (int ks = 0; ks < 4; ++ks) {
            f4v v0 = *(const f4v*)&xr[ks * 32 + q * 8];
            f4v v1 = *(const f4v*)&xr[ks * 32 + q * 8 + 4];
            for (int k = 0; k < 4; ++k) {
                short hh, ll;
                split2(v0[k], hh, ll); ah[ks][k] = hh;     al[ks][k] = ll;
                split2(v1[k], hh, ll); ah[ks][4 + k] = hh; al[ks][4 + k] = ll;
            }
        }
    }
    __syncthreads();

    f4v zero = {0.f, 0.f, 0.f, 0.f};
    f4v acc[8];
    for (int n = 0; n < 8; ++n) acc[n] = zero;

    for (int ks = 0; ks < 4; ++ks) {
        for (int nt = 0; nt < 8; ++nt) {
            int r = nt * 16 + c, cs = wsw(r, ks * 32 + q * 8);
            s8v bh = *(const s8v*)&sWh[r][cs];
            s8v bl = *(const s8v*)&sWl[r][cs];
            acc[nt] = mfma_bf16(ah[ks], bh, acc[nt]);
            acc[nt] = mfma_bf16(al[ks], bh, acc[nt]);
            acc[nt] = mfma_bf16(ah[ks], bl, acc[nt]);
        }
    }
    for (int nt = 0; nt < 8; ++nt) {
        float bv = bias[nt * 16 + c];
        for (int r = 0; r < 4; ++r) {
            float v = fmaxf(acc[nt][r] + bv, 0.0f);
            short hh, ll; split2(v, hh, ll);
            size_t o = (size_t)(row0 + wave * 16 + q * 4 + r) * 128 + nt * 16 + c;
            dsth[o] = hh;
            dstl[o] = ll;
        }
    }
}

// ---------------------------------------------------------------------------
// Flash attention: block = (local batch, 64-query tile), 4 waves x 16 rows.
// 16 j-tiles: S = Xp.Yp^T split-bf16 (3 MFMAs/term), fp32 online softmax,
// O += P.Y in f16 MFMA.
// ---------------------------------------------------------------------------
__global__ __launch_bounds__(BDIM) void attn_kernel(
    const float* __restrict__ Y, const unsigned char* __restrict__ nmask,
    const short* __restrict__ XPh, const short* __restrict__ XPl,
    const short* __restrict__ YPh, const short* __restrict__ YPl,
    float* __restrict__ out)
{
    __shared__ short    sYph[64][136];  // +8 pad: 2-way only
    __shared__ short    sYpl[64][136];
    __shared__ _Float16 sYt[128][72];   // y transposed [h][j], f16
    __shared__ _Float16 sP[64][72];     // C/D -> A round-trip (wave-private)

    const int bl = blockIdx.x >> 4;            // local batch 0..31
    const int ibase = (blockIdx.x & 15) * 64;
    const int t = threadIdx.x, wave = t >> 6, lane = t & 63;
    const int c = lane & 15, q = lane >> 4;
    const int mrow = bl * 1024;

    s8v afh[4], afl[4];
    {
        const short* xh = XPh + (size_t)(mrow + ibase + wave * 16 + c) * 128;
        const short* xl = XPl + (size_t)(mrow + ibase + wave * 16 + c) * 128;
        for (int ks = 0; ks < 4; ++ks) {
            afh[ks] = *(const s8v*)&xh[ks * 32 + q * 8];
            afl[ks] = *(const s8v*)&xl[ks * 32 + q * 8];
        }
    }

    f4v zero = {0.f, 0.f, 0.f, 0.f};
    float m_i[4], l_i[4];
    f4v o[8];
    for (int r = 0; r < 4; ++r) { m_i[r] = -INFINITY; l_i[r] = 0.f; }
    for (int h = 0; h < 8; ++h) o[h] = zero;

    for (int jt = 0; jt < 16; ++jt) {
        const int jbase = jt * 64;
        __syncthreads();

        // y_proj hi/lo tiles (bf16, 16B loads)
        for (int it = 0; it < 4; ++it) {
            int idx = t + it * BDIM;
            int r = idx >> 4, c8 = (idx & 15) * 8;
            *(s8v*)&sYph[r][c8] = *(const s8v*)&YPh[(size_t)(mrow + jbase + r) * 128 + c8];
        }
        for (int it = 0; it < 4; ++it) {
            int idx = t + it * BDIM;
            int r = idx >> 4, c8 = (idx & 15) * 8;
            *(s8v*)&sYpl[r][c8] = *(const s8v*)&YPl[(size_t)(mrow + jbase + r) * 128 + c8];
        }
        // original y -> f16, transposed. h-contiguous global reads (coalesced),
        // b64 LDS writes (8-way conflict on 8 ops/jt: negligible).
        for (int it = 0; it < 8; ++it) {
            int idx = t + it * BDIM;           // 0..2047
            int h = idx & 127, j0 = (idx >> 7) * 4;
            const float* yb = Y + (size_t)(mrow + jbase + j0) * 128 + h;
            h4v hv;
            hv[0] = (_Float16)yb[0];
            hv[1] = (_Float16)yb[128];
            hv[2] = (_Float16)yb[256];
            hv[3] = (_Float16)yb[384];
            *(h4v*)&sYt[h][j0] = hv;
        }
        __syncthreads();

        // S tile (16 rows x 64 cols per wave), split-bf16 3-term products
        f4v s[4];
        for (int nt = 0; nt < 4; ++nt) s[nt] = zero;
        for (int ks = 0; ks < 4; ++ks) {
            for (int nt = 0; nt < 4; ++nt) {
                s8v bh = *(const s8v*)&sYph[nt * 16 + c][ks * 32 + q * 8];
                s8v bl = *(const s8v*)&sYpl[nt * 16 + c][ks * 32 + q * 8];
                s[nt] = mfma_bf16(afh[ks], bh, s[nt]);
                s[nt] = mfma_bf16(afl[ks], bh, s[nt]);
                s[nt] = mfma_bf16(afh[ks], bl, s[nt]);
            }
        }

        // mask column j = jbase + nt*16 + c
        int mk[4];
        for (int nt = 0; nt < 4; ++nt) {
            mk[nt] = nmask[mrow + jbase + nt * 16 + c];
            if (mk[nt]) { s[nt][0] = -1e30f; s[nt][1] = -1e30f; s[nt][2] = -1e30f; s[nt][3] = -1e30f; }
        }

        // fp32 online softmax (rows live across lane&15 within each quad)
        float alpha[4];
        for (int r = 0; r < 4; ++r) {
            float mx = fmaxf(fmaxf(s[0][r], s[1][r]), fmaxf(s[2][r], s[3][r]));
            for (int off = 1; off < 16; off <<= 1)
                mx = fmaxf(mx, __shfl_xor(mx, off, 64));
            float mnew = fmaxf(m_i[r], mx);
            alpha[r] = __expf(m_i[r] - mnew);   // expf(-inf)=0 on first tile
            m_i[r] = mnew;
        }

        // P in f16; masked -> exactly 0; l from the f16-rounded P (cancels)
        float rs[4] = {0.f, 0.f, 0.f, 0.f};
        for (int nt = 0; nt < 4; ++nt) {
            for (int r = 0; r < 4; ++r) {
                float p = mk[nt] ? 0.f : __expf(s[nt][r] - m_i[r]);
                _Float16 ph = (_Float16)p;
                rs[r] += (float)ph;
                sP[wave * 16 + q * 4 + r][nt * 16 + c] = ph;
            }
        }
        for (int r = 0; r < 4; ++r) {
            float sum = rs[r];
            for (int off = 1; off < 16; off <<= 1)
                sum += __shfl_xor(sum, off, 64);
            l_i[r] = l_i[r] * alpha[r] + sum;
        }

        for (int h = 0; h < 8; ++h)
            for (int r = 0; r < 4; ++r)
                o[h][r] *= alpha[r];
        // PV in f16 (same-wave LDS write->read, compiler orders via lgkmcnt)
        for (int k2 = 0; k2 < 2; ++k2) {
            h8v a = *(const h8v*)&sP[wave * 16 + c][k2 * 32 + q * 8];
            for (int h = 0; h < 8; ++h) {
                h8v bb = *(const h8v*)&sYt[h * 16 + c][k2 * 32 + q * 8];
                o[h] = mfma_f16(a, bb, o[h]);
            }
        }
    }

    for (int h = 0; h < 8; ++h) {
        for (int r = 0; r < 4; ++r) {
            float v = o[h][r] / l_i[r];
            out[(size_t)(mrow + ibase + wave * 16 + q * 4 + r) * 128 + h * 16 + c] = v;
        }
    }
}

// ---------------------------------------------------------------------------
extern "C" void kernel_launch(void* const* d_in, const int* in_sizes, int n_in,
                              void* d_out, int out_size, void* d_ws, size_t ws_size,
                              hipStream_t stream) {
    const float* x    = (const float*)d_in[0];  // [64,1024,128] fp32
    const float* y    = (const float*)d_in[1];
    const unsigned int* mraw = (const unsigned int*)d_in[2];
    const float* W    = (const float*)d_in[3];  // [128,128] fp32
    const float* bias = (const float*)d_in[4];  // [128] fp32
    float* out = (float*)d_out;                 // [64,1024,128] fp32

    // ws layout (proven <= 32MB+64KB): nmask | XPh | XPl | YPh | YPl
    unsigned char* nmask = (unsigned char*)d_ws;
    short* XPh = (short*)((char*)d_ws + 65536);
    short* XPl = XPh + PLANE;
    short* YPh = XPl + PLANE;
    short* YPl = YPh + PLANE;

    mask_prep<<<1, 1024, 0, stream>>>(mraw, nmask);
    for (int g = 0; g < 2; ++g) {
        size_t ro = (size_t)g * GROUP_ROWS;
        proj_kernel<<<1024, BDIM, 0, stream>>>(x + ro * 128, y + ro * 128, W, bias,
                                               XPh, XPl, YPh, YPl);
        attn_kernel<<<512, BDIM, 0, stream>>>(y + ro * 128, nmask + ro,
                                              XPh, XPl, YPh, YPl, out + ro * 128);
    }
}

// Round 6
// 543.903 us; speedup vs baseline: 2.4396x; 2.4396x over previous
//
#include <hip/hip_runtime.h>
#include <hip/hip_bf16.h>

// ---------------------------------------------------------------------------
// SeqAttnMatch, fp32 in/out, B=64, L1=L2=1024, H=128.
// proj & QK in split-bf16 (hi+lo truncation split, 3 MFMAs); softmax fp32;
// PV in f16. W pre-split ONCE in prep. proj LDS 32KB, attn LDS 27.6KB
// (QK operands straight from L2), XCD-swizzled attn blocks.
// R5 bug fixed: W LDS staging covered only rows 0..31 (i<2 -> i<4).
// ---------------------------------------------------------------------------

typedef __attribute__((ext_vector_type(8))) short    s8v;  // 8 bf16 = 16B
typedef __attribute__((ext_vector_type(8))) _Float16 h8v;  // 8 f16 = 16B
typedef __attribute__((ext_vector_type(4))) _Float16 h4v;  // 4 f16 = 8B
typedef __attribute__((ext_vector_type(4))) float    f4v;

#define BDIM 256
#define GROUP_ROWS 32768          // 32 batches x 1024
#define PLANE ((size_t)GROUP_ROWS * 128)

__device__ __forceinline__ f4v mfma_bf16(s8v a, s8v b, f4v c) {
    return __builtin_amdgcn_mfma_f32_16x16x32_bf16(a, b, c, 0, 0, 0);
}
__device__ __forceinline__ f4v mfma_f16(h8v a, h8v b, f4v c) {
    return __builtin_amdgcn_mfma_f32_16x16x32_f16(a, b, c, 0, 0, 0);
}
// truncation split: v = bf16(hi) + bf16(lo) + O(2^-17 v). 3 VALU ops, no RNE.
__device__ __forceinline__ void tsplit(float v, short& hi, short& lo) {
    unsigned b = __builtin_bit_cast(unsigned, v);
    unsigned hb = b & 0xFFFF0000u;
    float res = v - __builtin_bit_cast(float, hb);
    hi = (short)(hb >> 16);
    lo = (short)(__builtin_bit_cast(unsigned, res) >> 16);
}

// ---------------------------------------------------------------------------
// prep: block 0 = mask normalize -> uint8 (detector proven in r3/r4);
//       block 1 = W trunc-split into swizzle-baked bf16 hi/lo planes.
// swizzle: within row r, chunk c8 -> ((c8>>3)^(r&15))<<3 | (c8&7)
// ---------------------------------------------------------------------------
__global__ __launch_bounds__(1024) void prep_kernel(
    const unsigned int* __restrict__ mraw, unsigned char* __restrict__ nm,
    const float* __restrict__ W, short* __restrict__ Whsw, short* __restrict__ Wlsw)
{
    if (blockIdx.x == 1) {
        for (int idx = threadIdx.x; idx < 16384; idx += 1024) {
            int r = idx >> 7, c = idx & 127;
            short hi, lo; tsplit(W[idx], hi, lo);
            int cs = (((c >> 3) ^ (r & 15)) << 3) | (c & 7);
            Whsw[r * 128 + cs] = hi;
            Wlsw[r * 128 + cs] = lo;
        }
        return;
    }
    __shared__ unsigned int sOrAll, sOrOdd;
    if (threadIdx.x == 0) { sOrAll = 0u; sOrOdd = 0u; }
    __syncthreads();
    unsigned int oa = 0u, oo = 0u;
    for (int i = threadIdx.x; i < 16384; i += 1024) {
        unsigned int v = mraw[i];
        oa |= v;
        if (i & 1) oo |= v;
    }
    atomicOr(&sOrAll, oa);
    atomicOr(&sOrOdd, oo);
    __syncthreads();
    const unsigned int orv = sOrAll, oro = sOrOdd;
    int mode;  // 0 = 4B stride, 1 = uint8, 2 = 2B stride, 3 = int64
    if (orv <= 1u)                       mode = (orv == 1u && oro == 0u) ? 3 : 0;
    else if ((orv & 0xFEFEFEFEu) == 0u)  mode = 1;
    else if ((orv & 0x0000FFFFu) == 0u)  mode = 0;
    else                                 mode = 2;
    const unsigned char*  b8  = (const unsigned char*)mraw;
    const unsigned short* b16 = (const unsigned short*)mraw;
    for (int j = threadIdx.x; j < 65536; j += 1024) {
        unsigned int v;
        if (mode == 0)      v = mraw[j];
        else if (mode == 1) v = b8[j];
        else if (mode == 2) v = b16[j];
        else                v = mraw[2 * j] | mraw[2 * j + 1];
        nm[j] = v ? 1 : 0;
    }
}

// ---------------------------------------------------------------------------
// Projection: block = 128 rows x 64-h half. LDS = W hi/lo half = 32KB.
// Grid 1024/group: [0,512) x rows, [512,1024) y rows; local = gid&511:
// row-block = local>>1, h-half = local&1. 4 waves x (2 sets of 16 rows).
// ---------------------------------------------------------------------------
__global__ __launch_bounds__(BDIM, 3) void proj_kernel(
    const float* __restrict__ X, const float* __restrict__ Y,
    const short* __restrict__ Whsw, const short* __restrict__ Wlsw,
    const float* __restrict__ bias,
    short* __restrict__ XPh, short* __restrict__ XPl,
    short* __restrict__ YPh, short* __restrict__ YPl)
{
    __shared__ short sW[2][64][128];   // [plane][row in h-half][k swizzled]

    const int gid = blockIdx.x;
    const float* src; short *dh, *dl; int local;
    if (gid < 512) { src = X; dh = XPh; dl = XPl; local = gid; }
    else           { src = Y; dh = YPh; dl = YPl; local = gid - 512; }
    const int row0 = (local >> 1) * 128, h0 = (local & 1) * 64;
    const int t = threadIdx.x, w = t >> 6, lane = t & 63, c = lane & 15, q = lane >> 4;

    // stage pre-split, pre-swizzled W halves: plain 16B copies.
    // Each plane-half = 64 rows x 128 = 8192 shorts -> 1024 chunks of 8
    // -> FOUR iterations of 256 threads (r5 bug: had 2, left rows 32..63 stale).
    {
        const short* g0 = Whsw + h0 * 128;
        const short* g1 = Wlsw + h0 * 128;
        short* l0 = &sW[0][0][0];
        short* l1 = &sW[1][0][0];
        for (int i = 0; i < 4; ++i) {
            int off = (t + i * BDIM) * 8;    // 0..8184
            *(s8v*)(l0 + off) = *(const s8v*)(g0 + off);
            *(s8v*)(l1 + off) = *(const s8v*)(g1 + off);
        }
    }

    // A fragments from global fp32, trunc-split in registers
    s8v ah[2][4], al[2][4];
    for (int set = 0; set < 2; ++set) {
        const float* xr = src + (size_t)(row0 + w * 32 + set * 16 + c) * 128;
        for (int ks = 0; ks < 4; ++ks) {
            f4v v0 = *(const f4v*)&xr[ks * 32 + q * 8];
            f4v v1 = *(const f4v*)&xr[ks * 32 + q * 8 + 4];
            for (int k = 0; k < 4; ++k) {
                short hh, ll;
                tsplit(v0[k], hh, ll); ah[set][ks][k] = hh;     al[set][ks][k] = ll;
                tsplit(v1[k], hh, ll); ah[set][ks][4 + k] = hh; al[set][ks][4 + k] = ll;
            }
        }
    }
    __syncthreads();

    f4v zero = {0.f, 0.f, 0.f, 0.f};
    f4v acc[2][4];
    for (int s_ = 0; s_ < 2; ++s_) for (int n = 0; n < 4; ++n) acc[s_][n] = zero;

    for (int ks = 0; ks < 4; ++ks) {
        s8v bh[4], bl[4];
        for (int nt = 0; nt < 4; ++nt) {
            int cs = (((ks * 4 + q) ^ c) << 3);       // baked swizzle, kofs&7==0
            bh[nt] = *(const s8v*)&sW[0][nt * 16 + c][cs];
            bl[nt] = *(const s8v*)&sW[1][nt * 16 + c][cs];
        }
        for (int set = 0; set < 2; ++set)
            for (int nt = 0; nt < 4; ++nt) {
                acc[set][nt] = mfma_bf16(ah[set][ks], bh[nt], acc[set][nt]);
                acc[set][nt] = mfma_bf16(al[set][ks], bh[nt], acc[set][nt]);
                acc[set][nt] = mfma_bf16(ah[set][ks], bl[nt], acc[set][nt]);
            }
    }

    for (int set = 0; set < 2; ++set)
        for (int nt = 0; nt < 4; ++nt) {
            float bv = bias[h0 + nt * 16 + c];
            for (int r = 0; r < 4; ++r) {
                float v = fmaxf(acc[set][nt][r] + bv, 0.0f);
                short hh, ll; tsplit(v, hh, ll);
                size_t o = (size_t)(row0 + w * 32 + set * 16 + q * 4 + r) * 128
                           + h0 + nt * 16 + c;
                dh[o] = hh;
                dl[o] = ll;
            }
        }
}

// ---------------------------------------------------------------------------
// Flash attention: block = (batch, 64-q-tile), XCD-swizzled so a batch's
// 16 i-tiles share an XCD (YP tiles L2-local). QK B-frags straight from
// global YP planes; LDS only y^T (f16) + P round-trip = 27.6KB.
// ---------------------------------------------------------------------------
__global__ __launch_bounds__(BDIM, 3) void attn_kernel(
    const float* __restrict__ Y, const unsigned char* __restrict__ nmask,
    const short* __restrict__ XPh, const short* __restrict__ XPl,
    const short* __restrict__ YPh, const short* __restrict__ YPl,
    float* __restrict__ out)
{
    __shared__ _Float16 sYt[128][72];   // y transposed [h][j], f16
    __shared__ _Float16 sP[64][72];     // C/D -> A round-trip (wave-private rows)

    // 512 blocks = 8 xcd x 16 itile x 4: batch = xcd + 8*(rest>>4)
    const int id = blockIdx.x;
    const int xcd = id & 7, rest = id >> 3;
    const int ibase = (rest & 15) * 64;
    const int bl = xcd + 8 * (rest >> 4);       // local batch 0..31
    const int t = threadIdx.x, wave = t >> 6, lane = t & 63;
    const int c = lane & 15, q = lane >> 4;
    const int mrow = bl * 1024;

    s8v afh[4], afl[4];
    {
        const short* xh = XPh + (size_t)(mrow + ibase + wave * 16 + c) * 128;
        const short* xl = XPl + (size_t)(mrow + ibase + wave * 16 + c) * 128;
        for (int ks = 0; ks < 4; ++ks) {
            afh[ks] = *(const s8v*)&xh[ks * 32 + q * 8];
            afl[ks] = *(const s8v*)&xl[ks * 32 + q * 8];
        }
    }

    f4v zero = {0.f, 0.f, 0.f, 0.f};
    float m_i[4], l_i[4];
    f4v o[8];
    for (int r = 0; r < 4; ++r) { m_i[r] = -INFINITY; l_i[r] = 0.f; }
    for (int h = 0; h < 8; ++h) o[h] = zero;

    for (int jt = 0; jt < 16; ++jt) {
        const int jbase = jt * 64;
        __syncthreads();   // prior iter's PV reads of sYt done

        // stage y -> f16 transposed (global loads coalesced; b64 LDS writes)
        for (int it = 0; it < 8; ++it) {
            int idx = t + it * BDIM;           // 0..2047
            int h = idx & 127, j0 = (idx >> 7) * 4;
            const float* yb = Y + (size_t)(mrow + jbase + j0) * 128 + h;
            h4v hv;
            hv[0] = (_Float16)yb[0];
            hv[1] = (_Float16)yb[128];
            hv[2] = (_Float16)yb[256];
            hv[3] = (_Float16)yb[384];
            *(h4v*)&sYt[h][j0] = hv;
        }
        // QK overlaps the staging stores (no LDS dependence): B from global L2
        f4v s[4];
        for (int nt = 0; nt < 4; ++nt) s[nt] = zero;
        int mk[4];
        for (int nt = 0; nt < 4; ++nt) {
            size_t boff = (size_t)(mrow + jbase + nt * 16 + c) * 128 + q * 8;
            const short* ph = YPh + boff;
            const short* pl_ = YPl + boff;
            s8v bh0 = *(const s8v*)ph,        bh1 = *(const s8v*)(ph + 32);
            s8v bh2 = *(const s8v*)(ph + 64), bh3 = *(const s8v*)(ph + 96);
            s8v bl0 = *(const s8v*)pl_,        bl1 = *(const s8v*)(pl_ + 32);
            s8v bl2 = *(const s8v*)(pl_ + 64), bl3 = *(const s8v*)(pl_ + 96);
            mk[nt] = nmask[mrow + jbase + nt * 16 + c];
            s[nt] = mfma_bf16(afh[0], bh0, s[nt]);
            s[nt] = mfma_bf16(afl[0], bh0, s[nt]);
            s[nt] = mfma_bf16(afh[0], bl0, s[nt]);
            s[nt] = mfma_bf16(afh[1], bh1, s[nt]);
            s[nt] = mfma_bf16(afl[1], bh1, s[nt]);
            s[nt] = mfma_bf16(afh[1], bl1, s[nt]);
            s[nt] = mfma_bf16(afh[2], bh2, s[nt]);
            s[nt] = mfma_bf16(afl[2], bh2, s[nt]);
            s[nt] = mfma_bf16(afh[2], bl2, s[nt]);
            s[nt] = mfma_bf16(afh[3], bh3, s[nt]);
            s[nt] = mfma_bf16(afl[3], bh3, s[nt]);
            s[nt] = mfma_bf16(afh[3], bl3, s[nt]);
            if (mk[nt]) { s[nt][0] = -1e30f; s[nt][1] = -1e30f; s[nt][2] = -1e30f; s[nt][3] = -1e30f; }
        }

        // fp32 online softmax (row r spread across lane&15 of each quad)
        float alpha[4];
        for (int r = 0; r < 4; ++r) {
            float mx = fmaxf(fmaxf(s[0][r], s[1][r]), fmaxf(s[2][r], s[3][r]));
            for (int off = 1; off < 16; off <<= 1)
                mx = fmaxf(mx, __shfl_xor(mx, off, 64));
            float mnew = fmaxf(m_i[r], mx);
            alpha[r] = __expf(m_i[r] - mnew);   // expf(-inf)=0 on first tile
            m_i[r] = mnew;
        }

        // P in f16; masked -> exactly 0; l from the f16-rounded P (cancels)
        float rs[4] = {0.f, 0.f, 0.f, 0.f};
        for (int nt = 0; nt < 4; ++nt) {
            for (int r = 0; r < 4; ++r) {
                float p = mk[nt] ? 0.f : __expf(s[nt][r] - m_i[r]);
                _Float16 ph = (_Float16)p;
                rs[r] += (float)ph;
                sP[wave * 16 + q * 4 + r][nt * 16 + c] = ph;
            }
        }
        for (int r = 0; r < 4; ++r) {
            float sum = rs[r];
            for (int off = 1; off < 16; off <<= 1)
                sum += __shfl_xor(sum, off, 64);
            l_i[r] = l_i[r] * alpha[r] + sum;
        }

        for (int h = 0; h < 8; ++h)
            for (int r = 0; r < 4; ++r)
                o[h][r] *= alpha[r];

        __syncthreads();   // sYt staging complete (stores above, all waves)
        // PV in f16 (sP same-wave rows: ordered by lgkmcnt, no barrier needed)
        for (int k2 = 0; k2 < 2; ++k2) {
            h8v a = *(const h8v*)&sP[wave * 16 + c][k2 * 32 + q * 8];
            for (int h = 0; h < 8; ++h) {
                h8v bb = *(const h8v*)&sYt[h * 16 + c][k2 * 32 + q * 8];
                o[h] = mfma_f16(a, bb, o[h]);
            }
        }
    }

    for (int h = 0; h < 8; ++h) {
        for (int r = 0; r < 4; ++r) {
            float v = o[h][r] / l_i[r];
            out[(size_t)(mrow + ibase + wave * 16 + q * 4 + r) * 128 + h * 16 + c] = v;
        }
    }
}

// ---------------------------------------------------------------------------
extern "C" void kernel_launch(void* const* d_in, const int* in_sizes, int n_in,
                              void* d_out, int out_size, void* d_ws, size_t ws_size,
                              hipStream_t stream) {
    const float* x    = (const float*)d_in[0];  // [64,1024,128] fp32
    const float* y    = (const float*)d_in[1];
    const unsigned int* mraw = (const unsigned int*)d_in[2];
    const float* W    = (const float*)d_in[3];  // [128,128] fp32
    const float* bias = (const float*)d_in[4];  // [128] fp32
    float* out = (float*)d_out;                 // [64,1024,128] fp32

    // ws: nmask 64KB | Whsw 32KB | Wlsw 32KB | XPh XPl YPh YPl (8MB each)
    unsigned char* nmask = (unsigned char*)d_ws;
    short* Whsw = (short*)((char*)d_ws + 65536);
    short* Wlsw = Whsw + 16384;
    short* XPh  = Wlsw + 16384;
    short* XPl  = XPh + PLANE;
    short* YPh  = XPl + PLANE;
    short* YPl  = YPh + PLANE;

    prep_kernel<<<2, 1024, 0, stream>>>(mraw, nmask, W, Whsw, Wlsw);
    for (int g = 0; g < 2; ++g) {
        size_t ro = (size_t)g * GROUP_ROWS;
        proj_kernel<<<1024, BDIM, 0, stream>>>(x + ro * 128, y + ro * 128,
                                               Whsw, Wlsw, bias,
                                               XPh, XPl, YPh, YPl);
        attn_kernel<<<512, BDIM, 0, stream>>>(y + ro * 128, nmask + ro,
                                              XPh, XPl, YPh, YPl, out + ro * 128);
    }
}

// Round 7
// 290.185 us; speedup vs baseline: 4.5725x; 1.8743x over previous
//
#include <hip/hip_runtime.h>
#include <hip/hip_bf16.h>

// ---------------------------------------------------------------------------
// SeqAttnMatch, fp32 in/out, B=64, L1=L2=1024, H=128.
// proj: split-bf16 (3-MFMA) GEMM -> fp32 preact -> f16 planes xp/yp.
// attn: QK in single f16 MFMA (score err ~0.002, x8 softmax amp = OK),
//       fp32 online softmax, PV f16. Single pass over all 64 batches
//       (planes are f16 so ws stays at the proven 32MB+128KB layout).
// ---------------------------------------------------------------------------

typedef __attribute__((ext_vector_type(8))) short    s8v;  // 8 bf16 = 16B
typedef __attribute__((ext_vector_type(8))) _Float16 h8v;  // 8 f16 = 16B
typedef __attribute__((ext_vector_type(4))) float    f4v;

#define BDIM 256

__device__ __forceinline__ f4v mfma_bf16(s8v a, s8v b, f4v c) {
    return __builtin_amdgcn_mfma_f32_16x16x32_bf16(a, b, c, 0, 0, 0);
}
__device__ __forceinline__ f4v mfma_f16(h8v a, h8v b, f4v c) {
    return __builtin_amdgcn_mfma_f32_16x16x32_f16(a, b, c, 0, 0, 0);
}
// truncation split: v = bf16(hi) + bf16(lo) + O(2^-17 v). 3 VALU ops, no RNE.
__device__ __forceinline__ void tsplit(float v, short& hi, short& lo) {
    unsigned b = __builtin_bit_cast(unsigned, v);
    unsigned hb = b & 0xFFFF0000u;
    float res = v - __builtin_bit_cast(float, hb);
    hi = (short)(hb >> 16);
    lo = (short)(__builtin_bit_cast(unsigned, res) >> 16);
}

// ---------------------------------------------------------------------------
// prep: block 0 = mask normalize -> uint8 (detector proven r3-r6);
//       block 1 = W trunc-split into swizzle-baked bf16 hi/lo planes.
// ---------------------------------------------------------------------------
__global__ __launch_bounds__(1024) void prep_kernel(
    const unsigned int* __restrict__ mraw, unsigned char* __restrict__ nm,
    const float* __restrict__ W, short* __restrict__ Whsw, short* __restrict__ Wlsw)
{
    if (blockIdx.x == 1) {
        for (int idx = threadIdx.x; idx < 16384; idx += 1024) {
            int r = idx >> 7, c = idx & 127;
            short hi, lo; tsplit(W[idx], hi, lo);
            int cs = (((c >> 3) ^ (r & 15)) << 3) | (c & 7);
            Whsw[r * 128 + cs] = hi;
            Wlsw[r * 128 + cs] = lo;
        }
        return;
    }
    __shared__ unsigned int sOrAll, sOrOdd;
    if (threadIdx.x == 0) { sOrAll = 0u; sOrOdd = 0u; }
    __syncthreads();
    unsigned int oa = 0u, oo = 0u;
    for (int i = threadIdx.x; i < 16384; i += 1024) {
        unsigned int v = mraw[i];
        oa |= v;
        if (i & 1) oo |= v;
    }
    atomicOr(&sOrAll, oa);
    atomicOr(&sOrOdd, oo);
    __syncthreads();
    const unsigned int orv = sOrAll, oro = sOrOdd;
    int mode;  // 0 = 4B stride, 1 = uint8, 2 = 2B stride, 3 = int64
    if (orv <= 1u)                       mode = (orv == 1u && oro == 0u) ? 3 : 0;
    else if ((orv & 0xFEFEFEFEu) == 0u)  mode = 1;
    else if ((orv & 0x0000FFFFu) == 0u)  mode = 0;
    else                                 mode = 2;
    const unsigned char*  b8  = (const unsigned char*)mraw;
    const unsigned short* b16 = (const unsigned short*)mraw;
    for (int j = threadIdx.x; j < 65536; j += 1024) {
        unsigned int v;
        if (mode == 0)      v = mraw[j];
        else if (mode == 1) v = b8[j];
        else if (mode == 2) v = b16[j];
        else                v = mraw[2 * j] | mraw[2 * j + 1];
        nm[j] = v ? 1 : 0;
    }
}

// ---------------------------------------------------------------------------
// Projection (single pass, all 64 batches): block = 128 rows x 64-h half.
// Grid 2048: [0,1024) x rows, [1024,2048) y rows. Split-bf16 3-MFMA GEMM,
// fp32 + bias + relu, stored as ONE f16 plane.
// ---------------------------------------------------------------------------
__global__ __launch_bounds__(BDIM, 4) void proj_kernel(
    const float* __restrict__ X, const float* __restrict__ Y,
    const short* __restrict__ Whsw, const short* __restrict__ Wlsw,
    const float* __restrict__ bias,
    _Float16* __restrict__ XPf, _Float16* __restrict__ YPf)
{
    __shared__ short sW[2][64][128];   // [plane][row in h-half][k swizzled]

    const int gid = blockIdx.x;
    const float* src; _Float16* dst; int local;
    if (gid < 1024) { src = X; dst = XPf; local = gid; }
    else            { src = Y; dst = YPf; local = gid - 1024; }
    const int row0 = (local >> 1) * 128, h0 = (local & 1) * 64;
    const int t = threadIdx.x, w = t >> 6, lane = t & 63, c = lane & 15, q = lane >> 4;

    // stage pre-split, pre-swizzled W halves: 8192 shorts/plane -> 4 iters
    {
        const short* g0 = Whsw + h0 * 128;
        const short* g1 = Wlsw + h0 * 128;
        short* l0 = &sW[0][0][0];
        short* l1 = &sW[1][0][0];
        for (int i = 0; i < 4; ++i) {
            int off = (t + i * BDIM) * 8;    // 0..8184
            *(s8v*)(l0 + off) = *(const s8v*)(g0 + off);
            *(s8v*)(l1 + off) = *(const s8v*)(g1 + off);
        }
    }

    // A fragments from global fp32, trunc-split in registers
    s8v ah[2][4], al[2][4];
    for (int set = 0; set < 2; ++set) {
        const float* xr = src + (size_t)(row0 + w * 32 + set * 16 + c) * 128;
        for (int ks = 0; ks < 4; ++ks) {
            f4v v0 = *(const f4v*)&xr[ks * 32 + q * 8];
            f4v v1 = *(const f4v*)&xr[ks * 32 + q * 8 + 4];
            for (int k = 0; k < 4; ++k) {
                short hh, ll;
                tsplit(v0[k], hh, ll); ah[set][ks][k] = hh;     al[set][ks][k] = ll;
                tsplit(v1[k], hh, ll); ah[set][ks][4 + k] = hh; al[set][ks][4 + k] = ll;
            }
        }
    }
    __syncthreads();

    f4v zero = {0.f, 0.f, 0.f, 0.f};
    f4v acc[2][4];
    for (int s_ = 0; s_ < 2; ++s_) for (int n = 0; n < 4; ++n) acc[s_][n] = zero;

    for (int ks = 0; ks < 4; ++ks) {
        s8v bh[4], bl[4];
        for (int nt = 0; nt < 4; ++nt) {
            int cs = (((ks * 4 + q) ^ c) << 3);       // baked swizzle
            bh[nt] = *(const s8v*)&sW[0][nt * 16 + c][cs];
            bl[nt] = *(const s8v*)&sW[1][nt * 16 + c][cs];
        }
        for (int set = 0; set < 2; ++set)
            for (int nt = 0; nt < 4; ++nt) {
                acc[set][nt] = mfma_bf16(ah[set][ks], bh[nt], acc[set][nt]);
                acc[set][nt] = mfma_bf16(al[set][ks], bh[nt], acc[set][nt]);
                acc[set][nt] = mfma_bf16(ah[set][ks], bl[nt], acc[set][nt]);
            }
    }

    for (int set = 0; set < 2; ++set)
        for (int nt = 0; nt < 4; ++nt) {
            float bv = bias[h0 + nt * 16 + c];
            for (int r = 0; r < 4; ++r) {
                float v = fmaxf(acc[set][nt][r] + bv, 0.0f);
                size_t o = (size_t)(row0 + w * 32 + set * 16 + q * 4 + r) * 128
                           + h0 + nt * 16 + c;
                dst[o] = (_Float16)v;
            }
        }
}

// ---------------------------------------------------------------------------
// Flash attention (single pass): 1024 blocks = 8 xcd x 16 itile x 8, so a
// batch's 16 i-tiles share an XCD. QK B-frags straight from the f16 YP
// plane in L2; LDS only y^T (f16) + P round-trip = 27.6KB -> 4 blocks/CU.
// ---------------------------------------------------------------------------
__global__ __launch_bounds__(BDIM, 4) void attn_kernel(
    const float* __restrict__ Y, const unsigned char* __restrict__ nmask,
    const _Float16* __restrict__ XPf, const _Float16* __restrict__ YPf,
    float* __restrict__ out)
{
    __shared__ _Float16 sYt[128][72];   // y transposed [h][j], f16
    __shared__ _Float16 sP[64][72];     // C/D -> A round-trip (wave-private rows)

    const int id = blockIdx.x;
    const int xcd = id & 7, rest = id >> 3;
    const int ibase = (rest & 15) * 64;
    const int b = xcd + 8 * (rest >> 4);        // batch 0..63
    const int t = threadIdx.x, wave = t >> 6, lane = t & 63;
    const int c = lane & 15, q = lane >> 4;
    const int mrow = b * 1024;

    h8v afrag[4];
    {
        const _Float16* xr = XPf + (size_t)(mrow + ibase + wave * 16 + c) * 128;
        for (int ks = 0; ks < 4; ++ks)
            afrag[ks] = *(const h8v*)&xr[ks * 32 + q * 8];
    }

    f4v zero = {0.f, 0.f, 0.f, 0.f};
    float m_i[4], l_i[4];
    f4v o[8];
    for (int r = 0; r < 4; ++r) { m_i[r] = -INFINITY; l_i[r] = 0.f; }
    for (int h = 0; h < 8; ++h) o[h] = zero;

    for (int jt = 0; jt < 16; ++jt) {
        const int jbase = jt * 64;
        __syncthreads();   // prior iter's PV reads of sYt done

        // stage y -> f16 transposed; b128 LDS writes (2-way conflict = free)
        for (int it = 0; it < 4; ++it) {
            int idx = t + it * BDIM;           // 0..1023
            int h = idx & 127, j0 = (idx >> 7) * 8;
            const float* yb = Y + (size_t)(mrow + jbase + j0) * 128 + h;
            h8v hv;
            for (int k = 0; k < 8; ++k) hv[k] = (_Float16)yb[k * 128];
            *(h8v*)&sYt[h][j0] = hv;
        }

        // QK from global f16 YP plane (overlaps staging stores; no LDS dep)
        f4v s[4];
        int mk[4];
        for (int nt = 0; nt < 4; ++nt) {
            const _Float16* pb = YPf + (size_t)(mrow + jbase + nt * 16 + c) * 128 + q * 8;
            h8v b0 = *(const h8v*)pb;
            h8v b1 = *(const h8v*)(pb + 32);
            h8v b2 = *(const h8v*)(pb + 64);
            h8v b3 = *(const h8v*)(pb + 96);
            mk[nt] = nmask[mrow + jbase + nt * 16 + c];
            f4v acc = zero;
            acc = mfma_f16(afrag[0], b0, acc);
            acc = mfma_f16(afrag[1], b1, acc);
            acc = mfma_f16(afrag[2], b2, acc);
            acc = mfma_f16(afrag[3], b3, acc);
            if (mk[nt]) { acc[0] = -1e30f; acc[1] = -1e30f; acc[2] = -1e30f; acc[3] = -1e30f; }
            s[nt] = acc;
        }

        // fp32 online softmax (row r spread across lane&15 of each quad)
        float alpha[4];
        for (int r = 0; r < 4; ++r) {
            float mx = fmaxf(fmaxf(s[0][r], s[1][r]), fmaxf(s[2][r], s[3][r]));
            for (int off = 1; off < 16; off <<= 1)
                mx = fmaxf(mx, __shfl_xor(mx, off, 64));
            float mnew = fmaxf(m_i[r], mx);
            alpha[r] = __expf(m_i[r] - mnew);   // expf(-inf)=0 on first tile
            m_i[r] = mnew;
        }

        // P in f16; masked -> exactly 0; l from the f16-rounded P (cancels)
        float rs[4] = {0.f, 0.f, 0.f, 0.f};
        for (int nt = 0; nt < 4; ++nt) {
            for (int r = 0; r < 4; ++r) {
                float p = mk[nt] ? 0.f : __expf(s[nt][r] - m_i[r]);
                _Float16 ph = (_Float16)p;
                rs[r] += (float)ph;
                sP[wave * 16 + q * 4 + r][nt * 16 + c] = ph;
            }
        }
        for (int r = 0; r < 4; ++r) {
            float sum = rs[r];
            for (int off = 1; off < 16; off <<= 1)
                sum += __shfl_xor(sum, off, 64);
            l_i[r] = l_i[r] * alpha[r] + sum;
        }

        for (int h = 0; h < 8; ++h)
            for (int r = 0; r < 4; ++r)
                o[h][r] *= alpha[r];

        __syncthreads();   // sYt staging complete (all waves)
        // PV in f16 (sP same-wave rows: ordered by lgkmcnt, no barrier)
        for (int k2 = 0; k2 < 2; ++k2) {
            h8v a = *(const h8v*)&sP[wave * 16 + c][k2 * 32 + q * 8];
            for (int h = 0; h < 8; ++h) {
                h8v bb = *(const h8v*)&sYt[h * 16 + c][k2 * 32 + q * 8];
                o[h] = mfma_f16(a, bb, o[h]);
            }
        }
    }

    for (int h = 0; h < 8; ++h) {
        for (int r = 0; r < 4; ++r) {
            float v = o[h][r] / l_i[r];
            out[(size_t)(mrow + ibase + wave * 16 + q * 4 + r) * 128 + h * 16 + c] = v;
        }
    }
}

// ---------------------------------------------------------------------------
extern "C" void kernel_launch(void* const* d_in, const int* in_sizes, int n_in,
                              void* d_out, int out_size, void* d_ws, size_t ws_size,
                              hipStream_t stream) {
    const float* x    = (const float*)d_in[0];  // [64,1024,128] fp32
    const float* y    = (const float*)d_in[1];
    const unsigned int* mraw = (const unsigned int*)d_in[2];
    const float* W    = (const float*)d_in[3];  // [128,128] fp32
    const float* bias = (const float*)d_in[4];  // [128] fp32
    float* out = (float*)d_out;                 // [64,1024,128] fp32

    // ws: nmask 64KB | Whsw 32KB | Wlsw 32KB | XPf 16MB | YPf 16MB
    // (same 32MB+128KB footprint proven in r4/r6)
    unsigned char* nmask = (unsigned char*)d_ws;
    short* Whsw = (short*)((char*)d_ws + 65536);
    short* Wlsw = Whsw + 16384;
    _Float16* XPf = (_Float16*)(Wlsw + 16384);
    _Float16* YPf = XPf + (size_t)64 * 1024 * 128;

    prep_kernel<<<2, 1024, 0, stream>>>(mraw, nmask, W, Whsw, Wlsw);
    proj_kernel<<<2048, BDIM, 0, stream>>>(x, y, Whsw, Wlsw, bias, XPf, YPf);
    attn_kernel<<<1024, BDIM, 0, stream>>>(y, nmask, XPf, YPf, out);
}

// Round 8
// 288.677 us; speedup vs baseline: 4.5964x; 1.0052x over previous
//
#include <hip/hip_runtime.h>
#include <hip/hip_bf16.h>

// ---------------------------------------------------------------------------
// SeqAttnMatch, fp32 in/out, B=64, L1=L2=1024, H=128.
// proj: split-bf16 (3-MFMA) GEMM -> f16 planes xp/yp (proven r6/r7).
// attn: QK f16 MFMA with B-frag/mask software prefetch; fp32 online softmax;
// PV f16 with XOR-chunk-swizzled conflict-free y^T LDS tile.
// ---------------------------------------------------------------------------

typedef __attribute__((ext_vector_type(8))) short    s8v;  // 8 bf16 = 16B
typedef __attribute__((ext_vector_type(8))) _Float16 h8v;  // 8 f16 = 16B
typedef __attribute__((ext_vector_type(4))) float    f4v;

#define BDIM 256

__device__ __forceinline__ f4v mfma_bf16(s8v a, s8v b, f4v c) {
    return __builtin_amdgcn_mfma_f32_16x16x32_bf16(a, b, c, 0, 0, 0);
}
__device__ __forceinline__ f4v mfma_f16(h8v a, h8v b, f4v c) {
    return __builtin_amdgcn_mfma_f32_16x16x32_f16(a, b, c, 0, 0, 0);
}
// truncation split: v = bf16(hi) + bf16(lo) + O(2^-17 v). 3 VALU ops, no RNE.
__device__ __forceinline__ void tsplit(float v, short& hi, short& lo) {
    unsigned b = __builtin_bit_cast(unsigned, v);
    unsigned hb = b & 0xFFFF0000u;
    float res = v - __builtin_bit_cast(float, hb);
    hi = (short)(hb >> 16);
    lo = (short)(__builtin_bit_cast(unsigned, res) >> 16);
}

// ---------------------------------------------------------------------------
// prep: block 0 = mask normalize -> uint8 (proven r3-r7);
//       block 1 = W trunc-split into swizzle-baked bf16 hi/lo planes.
// ---------------------------------------------------------------------------
__global__ __launch_bounds__(1024) void prep_kernel(
    const unsigned int* __restrict__ mraw, unsigned char* __restrict__ nm,
    const float* __restrict__ W, short* __restrict__ Whsw, short* __restrict__ Wlsw)
{
    if (blockIdx.x == 1) {
        for (int idx = threadIdx.x; idx < 16384; idx += 1024) {
            int r = idx >> 7, c = idx & 127;
            short hi, lo; tsplit(W[idx], hi, lo);
            int cs = (((c >> 3) ^ (r & 15)) << 3) | (c & 7);
            Whsw[r * 128 + cs] = hi;
            Wlsw[r * 128 + cs] = lo;
        }
        return;
    }
    __shared__ unsigned int sOrAll, sOrOdd;
    if (threadIdx.x == 0) { sOrAll = 0u; sOrOdd = 0u; }
    __syncthreads();
    unsigned int oa = 0u, oo = 0u;
    for (int i = threadIdx.x; i < 16384; i += 1024) {
        unsigned int v = mraw[i];
        oa |= v;
        if (i & 1) oo |= v;
    }
    atomicOr(&sOrAll, oa);
    atomicOr(&sOrOdd, oo);
    __syncthreads();
    const unsigned int orv = sOrAll, oro = sOrOdd;
    int mode;  // 0 = 4B stride, 1 = uint8, 2 = 2B stride, 3 = int64
    if (orv <= 1u)                       mode = (orv == 1u && oro == 0u) ? 3 : 0;
    else if ((orv & 0xFEFEFEFEu) == 0u)  mode = 1;
    else if ((orv & 0x0000FFFFu) == 0u)  mode = 0;
    else                                 mode = 2;
    const unsigned char*  b8  = (const unsigned char*)mraw;
    const unsigned short* b16 = (const unsigned short*)mraw;
    for (int j = threadIdx.x; j < 65536; j += 1024) {
        unsigned int v;
        if (mode == 0)      v = mraw[j];
        else if (mode == 1) v = b8[j];
        else if (mode == 2) v = b16[j];
        else                v = mraw[2 * j] | mraw[2 * j + 1];
        nm[j] = v ? 1 : 0;
    }
}

// ---------------------------------------------------------------------------
// Projection (all 64 batches): block = 128 rows x 64-h half, 2048 blocks.
// Split-bf16 3-MFMA GEMM, fp32 + bias + relu, stored as ONE f16 plane.
// ---------------------------------------------------------------------------
__global__ __launch_bounds__(BDIM, 4) void proj_kernel(
    const float* __restrict__ X, const float* __restrict__ Y,
    const short* __restrict__ Whsw, const short* __restrict__ Wlsw,
    const float* __restrict__ bias,
    _Float16* __restrict__ XPf, _Float16* __restrict__ YPf)
{
    __shared__ short sW[2][64][128];   // [plane][row in h-half][k swizzled]

    const int gid = blockIdx.x;
    const float* src; _Float16* dst; int local;
    if (gid < 1024) { src = X; dst = XPf; local = gid; }
    else            { src = Y; dst = YPf; local = gid - 1024; }
    const int row0 = (local >> 1) * 128, h0 = (local & 1) * 64;
    const int t = threadIdx.x, w = t >> 6, lane = t & 63, c = lane & 15, q = lane >> 4;

    {
        const short* g0 = Whsw + h0 * 128;
        const short* g1 = Wlsw + h0 * 128;
        short* l0 = &sW[0][0][0];
        short* l1 = &sW[1][0][0];
        for (int i = 0; i < 4; ++i) {
            int off = (t + i * BDIM) * 8;    // 0..8184
            *(s8v*)(l0 + off) = *(const s8v*)(g0 + off);
            *(s8v*)(l1 + off) = *(const s8v*)(g1 + off);
        }
    }

    s8v ah[2][4], al[2][4];
    for (int set = 0; set < 2; ++set) {
        const float* xr = src + (size_t)(row0 + w * 32 + set * 16 + c) * 128;
        for (int ks = 0; ks < 4; ++ks) {
            f4v v0 = *(const f4v*)&xr[ks * 32 + q * 8];
            f4v v1 = *(const f4v*)&xr[ks * 32 + q * 8 + 4];
            for (int k = 0; k < 4; ++k) {
                short hh, ll;
                tsplit(v0[k], hh, ll); ah[set][ks][k] = hh;     al[set][ks][k] = ll;
                tsplit(v1[k], hh, ll); ah[set][ks][4 + k] = hh; al[set][ks][4 + k] = ll;
            }
        }
    }
    __syncthreads();

    f4v zero = {0.f, 0.f, 0.f, 0.f};
    f4v acc[2][4];
    for (int s_ = 0; s_ < 2; ++s_) for (int n = 0; n < 4; ++n) acc[s_][n] = zero;

    for (int ks = 0; ks < 4; ++ks) {
        s8v bh[4], bl[4];
        for (int nt = 0; nt < 4; ++nt) {
            int cs = (((ks * 4 + q) ^ c) << 3);       // baked swizzle
            bh[nt] = *(const s8v*)&sW[0][nt * 16 + c][cs];
            bl[nt] = *(const s8v*)&sW[1][nt * 16 + c][cs];
        }
        for (int set = 0; set < 2; ++set)
            for (int nt = 0; nt < 4; ++nt) {
                acc[set][nt] = mfma_bf16(ah[set][ks], bh[nt], acc[set][nt]);
                acc[set][nt] = mfma_bf16(al[set][ks], bh[nt], acc[set][nt]);
                acc[set][nt] = mfma_bf16(ah[set][ks], bl[nt], acc[set][nt]);
            }
    }

    for (int set = 0; set < 2; ++set)
        for (int nt = 0; nt < 4; ++nt) {
            float bv = bias[h0 + nt * 16 + c];
            for (int r = 0; r < 4; ++r) {
                float v = fmaxf(acc[set][nt][r] + bv, 0.0f);
                size_t o = (size_t)(row0 + w * 32 + set * 16 + q * 4 + r) * 128
                           + h0 + nt * 16 + c;
                dst[o] = (_Float16)v;
            }
        }
}

// ---------------------------------------------------------------------------
// Flash attention: 1024 blocks = 8 xcd x 16 itile x 8 (batch i-tiles share
// an XCD). QK B-frags from f16 YP plane in L2 with k0/k1+mask prefetched one
// j-tile ahead (issued after barrier B, drained during PV / barrier A).
// sYt XOR-chunk swizzled (conflict-free b128 writes AND reads), no pad.
// ---------------------------------------------------------------------------
__global__ __launch_bounds__(BDIM, 4) void attn_kernel(
    const float* __restrict__ Y, const unsigned char* __restrict__ nmask,
    const _Float16* __restrict__ XPf, const _Float16* __restrict__ YPf,
    float* __restrict__ out)
{
    __shared__ _Float16 sYt[128][64];   // y^T, chunk c0 stored at c0^(h&7)
    __shared__ _Float16 sP[64][72];     // C/D -> A round-trip (wave-private rows)

    const int id = blockIdx.x;
    const int xcd = id & 7, rest = id >> 3;
    const int ibase = (rest & 15) * 64;
    const int b = xcd + 8 * (rest >> 4);        // batch 0..63
    const int t = threadIdx.x, wave = t >> 6, lane = t & 63;
    const int c = lane & 15, q = lane >> 4;
    const int mrow = b * 1024;

    h8v afrag[4];
    {
        const _Float16* xr = XPf + (size_t)(mrow + ibase + wave * 16 + c) * 128;
        for (int ks = 0; ks < 4; ++ks)
            afrag[ks] = *(const h8v*)&xr[ks * 32 + q * 8];
    }

    // prefetch state for the CURRENT j-tile: B k-blocks 0,1 + mask
    h8v bpre[4][2];
    int mk[4];
    for (int nt = 0; nt < 4; ++nt) {
        const _Float16* pb = YPf + (size_t)(mrow + nt * 16 + c) * 128 + q * 8;
        bpre[nt][0] = *(const h8v*)pb;
        bpre[nt][1] = *(const h8v*)(pb + 32);
        mk[nt] = nmask[mrow + nt * 16 + c];
    }

    f4v zero = {0.f, 0.f, 0.f, 0.f};
    float m_i[4], l_i[4];
    f4v o[8];
    for (int r = 0; r < 4; ++r) { m_i[r] = -INFINITY; l_i[r] = 0.f; }
    for (int h = 0; h < 8; ++h) o[h] = zero;

    for (int jt = 0; jt < 16; ++jt) {
        const int jbase = jt * 64;
        __syncthreads();   // prior PV reads done; prefetch loads drained

        // stage y -> f16 transposed, XOR-chunk swizzle (conflict-free b128)
        for (int it = 0; it < 4; ++it) {
            int idx = t + it * BDIM;           // 0..1023 = 128 h x 8 chunks
            int h = idx & 127, c0 = idx >> 7;
            const float* yb = Y + (size_t)(mrow + jbase + c0 * 8) * 128 + h;
            h8v hv;
            for (int k = 0; k < 8; ++k) hv[k] = (_Float16)yb[k * 128];
            *(h8v*)&sYt[h][(c0 ^ (h & 7)) << 3] = hv;
        }

        // QK: k0/k1 from prefetch regs, k2/k3 fresh (hidden behind 8 MFMAs)
        f4v s[4];
        for (int nt = 0; nt < 4; ++nt) {
            const _Float16* pb = YPf + (size_t)(mrow + jbase + nt * 16 + c) * 128 + q * 8;
            h8v b2 = *(const h8v*)(pb + 64);
            h8v b3 = *(const h8v*)(pb + 96);
            f4v acc = zero;
            acc = mfma_f16(afrag[0], bpre[nt][0], acc);
            acc = mfma_f16(afrag[1], bpre[nt][1], acc);
            acc = mfma_f16(afrag[2], b2, acc);
            acc = mfma_f16(afrag[3], b3, acc);
            if (mk[nt]) { acc[0] = -1e30f; acc[1] = -1e30f; acc[2] = -1e30f; acc[3] = -1e30f; }
            s[nt] = acc;
        }

        // fp32 online softmax (row r spread across lane&15 of each quad)
        float alpha[4];
        for (int r = 0; r < 4; ++r) {
            float mx = fmaxf(fmaxf(s[0][r], s[1][r]), fmaxf(s[2][r], s[3][r]));
            for (int off = 1; off < 16; off <<= 1)
                mx = fmaxf(mx, __shfl_xor(mx, off, 64));
            float mnew = fmaxf(m_i[r], mx);
            alpha[r] = __expf(m_i[r] - mnew);   // expf(-inf)=0 on first tile
            m_i[r] = mnew;
        }

        // P in f16; masked -> exactly 0; l from the f16-rounded P (cancels)
        float rs[4] = {0.f, 0.f, 0.f, 0.f};
        for (int nt = 0; nt < 4; ++nt) {
            for (int r = 0; r < 4; ++r) {
                float p = mk[nt] ? 0.f : __expf(s[nt][r] - m_i[r]);
                _Float16 ph = (_Float16)p;
                rs[r] += (float)ph;
                sP[wave * 16 + q * 4 + r][nt * 16 + c] = ph;
            }
        }
        for (int r = 0; r < 4; ++r) {
            float sum = rs[r];
            for (int off = 1; off < 16; off <<= 1)
                sum += __shfl_xor(sum, off, 64);
            l_i[r] = l_i[r] * alpha[r] + sum;
        }

        for (int h = 0; h < 8; ++h)
            for (int r = 0; r < 4; ++r)
                o[h][r] *= alpha[r];

        __syncthreads();   // sYt staging complete (all waves)

        // refill prefetch for jt+1 (issues VMEM now; drains by next barrier A)
        if (jt < 15) {
            const int jn = jbase + 64;
            for (int nt = 0; nt < 4; ++nt) {
                const _Float16* pb = YPf + (size_t)(mrow + jn + nt * 16 + c) * 128 + q * 8;
                bpre[nt][0] = *(const h8v*)pb;
                bpre[nt][1] = *(const h8v*)(pb + 32);
                mk[nt] = nmask[mrow + jn + nt * 16 + c];
            }
        }

        // PV in f16 (sP same-wave rows ordered by lgkmcnt; sYt swizzled read)
        for (int k2 = 0; k2 < 2; ++k2) {
            h8v a = *(const h8v*)&sP[wave * 16 + c][k2 * 32 + q * 8];
            for (int hb = 0; hb < 8; ++hb) {
                h8v bb = *(const h8v*)&sYt[hb * 16 + c][(((k2 << 2) + q) ^ (c & 7)) << 3];
                o[hb] = mfma_f16(a, bb, o[hb]);
            }
        }
    }

    for (int h = 0; h < 8; ++h) {
        for (int r = 0; r < 4; ++r) {
            float v = o[h][r] / l_i[r];
            out[(size_t)(mrow + ibase + wave * 16 + q * 4 + r) * 128 + h * 16 + c] = v;
        }
    }
}

// ---------------------------------------------------------------------------
extern "C" void kernel_launch(void* const* d_in, const int* in_sizes, int n_in,
                              void* d_out, int out_size, void* d_ws, size_t ws_size,
                              hipStream_t stream) {
    const float* x    = (const float*)d_in[0];  // [64,1024,128] fp32
    const float* y    = (const float*)d_in[1];
    const unsigned int* mraw = (const unsigned int*)d_in[2];
    const float* W    = (const float*)d_in[3];  // [128,128] fp32
    const float* bias = (const float*)d_in[4];  // [128] fp32
    float* out = (float*)d_out;                 // [64,1024,128] fp32

    // ws: nmask 64KB | Whsw 32KB | Wlsw 32KB | XPf 16MB | YPf 16MB
    unsigned char* nmask = (unsigned char*)d_ws;
    short* Whsw = (short*)((char*)d_ws + 65536);
    short* Wlsw = Whsw + 16384;
    _Float16* XPf = (_Float16*)(Wlsw + 16384);
    _Float16* YPf = XPf + (size_t)64 * 1024 * 128;

    prep_kernel<<<2, 1024, 0, stream>>>(mraw, nmask, W, Whsw, Wlsw);
    proj_kernel<<<2048, BDIM, 0, stream>>>(x, y, Whsw, Wlsw, bias, XPf, YPf);
    attn_kernel<<<1024, BDIM, 0, stream>>>(y, nmask, XPf, YPf, out);
}